// Round 1
// baseline (229.044 us; speedup 1.0000x reference)
//
#include <hip/hip_runtime.h>

#define DIM 4096
#define HAD_SCALE 0.015625f  // 1/sqrt(4096) = 1/64

// XOR swizzle: injects bits 6-8 into bank bits 2-4. Bijective on [0,4096),
// preserves 16B (float4) contiguity since bits 0-1 untouched and the mask
// depends only on bits >= 6.
__device__ __forceinline__ int swz(int a) {
    return a ^ (((a >> 6) & 7) << 2);
}

// Full 4-bit Walsh-Hadamard transform over 16 registers. Butterflies on
// distinct bits commute, so index<->bit assignment is arbitrary as long as
// all 12 bits are covered exactly once across all phases.
__device__ __forceinline__ void fwht16(float r[16]) {
#pragma unroll
    for (int s = 1; s < 16; s <<= 1) {
#pragma unroll
        for (int i = 0; i < 16; i++) {
            if ((i & s) == 0) {
                float a = r[i];
                float b = r[i ^ s];
                r[i]     = a + b;   // bit==0 slot: a + b  (matches reference)
                r[i ^ s] = a - b;   // bit==1 slot: a - b
            }
        }
    }
}

// DPP quad_perm lane shuffle (VALU pipe, no LDS traffic).
// CTRL 0xB1 = {1,0,3,2} = lane xor 1;  CTRL 0x4E = {2,3,0,1} = lane xor 2.
template <int CTRL>
__device__ __forceinline__ float qperm(float v) {
    return __int_as_float(
        __builtin_amdgcn_mov_dpp(__float_as_int(v), CTRL, 0xF, 0xF, false));
}

// Cross-lane butterfly: lanes with (bit==0) hold 'a', (bit==1) hold 'b'.
// new = own*sign + partner  ->  a+b on low lane, a-b on high lane.
// fmaf with sign=+-1 is bit-exact vs add/sub.

// One block per 4096-float row. 256 threads x 16 floats.
// Bit schedule (12 butterfly bits, each exactly once):
//   load-layout fwht16      : bits {0,1,10,11}
//   DPP quad_perm xor1/xor2 : bits {2,3}      (lane bits 0,1)
//   -- single LDS transpose + single barrier --
//   fwht16 on regs          : bits {4,5,6,7}
//   ds_swizzle xor16        : bit  {8}        (lane bit 4)
//   shfl_xor 32             : bit  {9}        (lane bit 5)
__global__ __launch_bounds__(256) void fwht_kernel(const float* __restrict__ x,
                                                   float* __restrict__ y) {
    __shared__ float lds[DIM];  // 16 KiB -> 8 blocks/CU (wave-slot capped)
    const int t = threadIdx.x;
    const size_t row = blockIdx.x;
    const float* xin = x + row * DIM;
    float* yout = y + row * DIM;

    float r[16];

    // ---- Load: thread t gets j = 1024*c + 4*t + e  (c,e in [0,4)).
    // Coalesced: each wave instruction reads a contiguous 1 KiB segment.
    const float4* __restrict__ x4 = (const float4*)xin;
#pragma unroll
    for (int c = 0; c < 4; c++) {
        float4 v = x4[c * 256 + t];
        r[4 * c + 0] = v.x;
        r[4 * c + 1] = v.y;
        r[4 * c + 2] = v.z;
        r[4 * c + 3] = v.w;
    }
    fwht16(r);  // bits {0,1} (e) and {10,11} (c)

    // ---- bits {2,3}: j bit2 = lane bit0, j bit3 = lane bit1 (j = 4t+1024c).
    const float s1 = (t & 1) ? -1.f : 1.f;
#pragma unroll
    for (int i = 0; i < 16; i++) {
        float p = qperm<0xB1>(r[i]);           // partner from lane^1
        r[i] = __builtin_fmaf(r[i], s1, p);
    }
    const float s2 = (t & 2) ? -1.f : 1.f;
#pragma unroll
    for (int i = 0; i < 16; i++) {
        float p = qperm<0x4E>(r[i]);           // partner from lane^2
        r[i] = __builtin_fmaf(r[i], s2, p);
    }

    // ---- Single transpose: b128 writes, conflict-free under swz.
#pragma unroll
    for (int c = 0; c < 4; c++) {
        int a = swz(4 * t + 1024 * c);
        *(float4*)&lds[a] = make_float4(r[4 * c + 0], r[4 * c + 1],
                                        r[4 * c + 2], r[4 * c + 3]);
    }
    __syncthreads();  // the ONLY barrier

    // ---- New ownership: j = (t&15) + 16*m + 256*(t>>4).
    //   j bits 0-3 = lane bits 0-3, j bits 4-7 = m (regs),
    //   j bits 8,9 = lane bits 4,5, j bits 10,11 = wave id (done in P1).
    // Bank check: bank = {t0, t1, t2^m2, t3^m3, m0^t4} -> 2-way max (free).
    const int base = (t & 15) + ((t >> 4) << 8);
#pragma unroll
    for (int m = 0; m < 16; m++) r[m] = lds[swz(base + (m << 4))];
    fwht16(r);  // bits {4,5,6,7}

    // ---- bit 8: lane xor 16 via ds_swizzle bit-mode (0x401F = xor 0x10).
    const float s16 = (t & 16) ? -1.f : 1.f;
#pragma unroll
    for (int i = 0; i < 16; i++) {
        float p = __int_as_float(
            __builtin_amdgcn_ds_swizzle(__float_as_int(r[i]), 0x401F));
        r[i] = __builtin_fmaf(r[i], s16, p);
    }
    // ---- bit 9: lane xor 32.
    const float s32 = (t & 32) ? -1.f : 1.f;
#pragma unroll
    for (int i = 0; i < 16; i++) {
        float p = __shfl_xor(r[i], 32, 64);
        r[i] = __builtin_fmaf(r[i], s32, p);
    }

    // ---- Store: fixed m -> four full 64B cache lines per wave instruction;
    // the 16 stores cover a contiguous 4 KiB region per wave.
#pragma unroll
    for (int m = 0; m < 16; m++)
        yout[base + (m << 4)] = r[m] * HAD_SCALE;
}

extern "C" void kernel_launch(void* const* d_in, const int* in_sizes, int n_in,
                              void* d_out, int out_size, void* d_ws, size_t ws_size,
                              hipStream_t stream) {
    const float* x = (const float*)d_in[0];
    float* y = (float*)d_out;
    const int n = in_sizes[0];
    const int rows = n / DIM;  // 8192 for (4, 2048, 4096)
    fwht_kernel<<<rows, 256, 0, stream>>>(x, y);
}

// Round 3
// 226.458 us; speedup vs baseline: 1.0114x; 1.0114x over previous
//
#include <hip/hip_runtime.h>

#define DIM 4096
#define HAD_SCALE 0.015625f  // 1/sqrt(4096) = 1/64

// Full 4-bit Walsh-Hadamard transform over 16 registers (bits of the reg
// index). Butterflies on distinct bits commute, so the index<->bit
// assignment is arbitrary as long as all 12 j-bits are covered once.
__device__ __forceinline__ void fwht16(float r[16]) {
#pragma unroll
    for (int s = 1; s < 16; s <<= 1) {
#pragma unroll
        for (int i = 0; i < 16; i++) {
            if ((i & s) == 0) {
                float a = r[i];
                float b = r[i ^ s];
                r[i]     = a + b;   // bit==0 slot: a + b  (matches reference)
                r[i ^ s] = a - b;   // bit==1 slot: a - b
            }
        }
    }
}

// DPP quad_perm lane shuffle (VALU pipe). 0xB1 = lane^1, 0x4E = lane^2.
template <int CTRL>
__device__ __forceinline__ float qperm(float v) {
    return __int_as_float(
        __builtin_amdgcn_mov_dpp(__float_as_int(v), CTRL, 0xF, 0xF, false));
}

// ds_swizzle bit-mode lane xor (LDS pipe, no storage). offset encoding:
// (xor<<10)|(or<<5)|and, and=0x1F. xor4=0x101F, xor8=0x201F, xor16=0x401F.
template <int OFS>
__device__ __forceinline__ float lswz(float v) {
    return __int_as_float(
        __builtin_amdgcn_ds_swizzle(__float_as_int(v), OFS));
}

// Cross-lane butterfly: new = own*sign + partner -> a+b on the bit==0 lane,
// a-b on the bit==1 lane. fma with sign=+-1 is bit-exact vs add/sub.

// One block per 4096-float row, 256 threads x 16 floats.
// Layout is FIXED for the whole kernel: j = e + 4*lane + 256*wave + 1024*c
//   (e = float4 element, lane = t&63, wave = t>>6, c = reg group).
// So both the load AND the store are 4x lane-sequential float4 <-> full
// 1 KiB per wave instruction, matching the pattern the 6.7 TB/s fills use.
// Bit schedule (each of the 12 j-bits exactly once):
//   fwht16 on regs          : bits {0,1,10,11}   (e, c)
//   DPP quad_perm xor1/xor2 : bits {2,3}         (lane bits 0,1)
//   ds_swizzle xor4/8/16    : bits {4,5,6}       (lane bits 2,3,4)
//   shfl_xor 32             : bit  {7}           (lane bit 5)
//   LDS 4-point combine     : bits {8,9}         (wave bits) - one barrier
__global__ __launch_bounds__(256) void fwht_kernel(const float* __restrict__ x,
                                                   float* __restrict__ y) {
    __shared__ float lds[DIM];  // 16 KiB -> 8 blocks/CU (wave-slot capped)
    const int t = threadIdx.x;
    const size_t row = blockIdx.x;
    const float4* __restrict__ x4 = (const float4*)(x + row * DIM);
    float4* __restrict__ y4 = (float4*)(y + row * DIM);

    float r[16];

    // ---- Load: r[4c+e] = j at (e + 4*lane + 256*wave + 1024*c).
    // Each wave instruction reads a contiguous 1 KiB segment.
#pragma unroll
    for (int c = 0; c < 4; c++) {
        float4 v = x4[c * 256 + t];
        r[4 * c + 0] = v.x;
        r[4 * c + 1] = v.y;
        r[4 * c + 2] = v.z;
        r[4 * c + 3] = v.w;
    }
    fwht16(r);  // bits {0,1} (e) and {10,11} (c)

    // ---- bits {2,3}: lane xor1 / xor2 via DPP (VALU pipe).
    const float sA = (t & 1) ? -1.f : 1.f;
#pragma unroll
    for (int i = 0; i < 16; i++)
        r[i] = __builtin_fmaf(r[i], sA, qperm<0xB1>(r[i]));
    const float sB = (t & 2) ? -1.f : 1.f;
#pragma unroll
    for (int i = 0; i < 16; i++)
        r[i] = __builtin_fmaf(r[i], sB, qperm<0x4E>(r[i]));

    // ---- bits {4,5,6}: lane xor4 / xor8 / xor16 via ds_swizzle.
    const float sC = (t & 4) ? -1.f : 1.f;
#pragma unroll
    for (int i = 0; i < 16; i++)
        r[i] = __builtin_fmaf(r[i], sC, lswz<0x101F>(r[i]));
    const float sD = (t & 8) ? -1.f : 1.f;
#pragma unroll
    for (int i = 0; i < 16; i++)
        r[i] = __builtin_fmaf(r[i], sD, lswz<0x201F>(r[i]));
    const float sE = (t & 16) ? -1.f : 1.f;
#pragma unroll
    for (int i = 0; i < 16; i++)
        r[i] = __builtin_fmaf(r[i], sE, lswz<0x401F>(r[i]));

    // ---- bit {7}: lane xor32.
    const float sF = (t & 32) ? -1.f : 1.f;
#pragma unroll
    for (int i = 0; i < 16; i++)
        r[i] = __builtin_fmaf(r[i], sF, __shfl_xor(r[i], 32, 64));

    // ---- bits {8,9} (wave bits): one LDS round trip, one barrier.
    // Write own values at their j addresses: float4 base = 4t + 1024c.
    // Lane-sequential 1 KiB per wave instruction -> conflict-free b128,
    // no swizzle needed.
#pragma unroll
    for (int c = 0; c < 4; c++)
        *(float4*)&lds[4 * t + 1024 * c] =
            make_float4(r[4 * c + 0], r[4 * c + 1], r[4 * c + 2], r[4 * c + 3]);
    __syncthreads();  // the ONLY barrier

    // 4-point Hadamard across the 4 wave slots:
    //   u0 = s0*q[w] + q[w^1]; u1 = s0*q[w^2] + q[w^3]; res = s1*u0 + u1
    // where s0 flips on j-bit8 (t bit 6), s1 on j-bit9 (t bit 7).
    const float s0 = (t & 64) ? -1.f : 1.f;
    const float s1 = (t & 128) ? -1.f : 1.f;
    const int a = 4 * t;  // bits 8,9 of 'a' encode the wave id
#pragma unroll
    for (int c = 0; c < 4; c++) {
        const int b = 1024 * c;
        // Partner reads: also lane-sequential 1 KiB per instruction.
        float4 p1 = *(const float4*)&lds[(a ^ 256) + b];
        float4 p2 = *(const float4*)&lds[(a ^ 512) + b];
        float4 p3 = *(const float4*)&lds[(a ^ 768) + b];
        float4 res;
        res.x = __builtin_fmaf(__builtin_fmaf(r[4 * c + 0], s0, p1.x), s1,
                               __builtin_fmaf(p2.x, s0, p3.x)) * HAD_SCALE;
        res.y = __builtin_fmaf(__builtin_fmaf(r[4 * c + 1], s0, p1.y), s1,
                               __builtin_fmaf(p2.y, s0, p3.y)) * HAD_SCALE;
        res.z = __builtin_fmaf(__builtin_fmaf(r[4 * c + 2], s0, p1.z), s1,
                               __builtin_fmaf(p2.z, s0, p3.z)) * HAD_SCALE;
        res.w = __builtin_fmaf(__builtin_fmaf(r[4 * c + 3], s0, p1.w), s1,
                               __builtin_fmaf(p2.w, s0, p3.w)) * HAD_SCALE;
        // ---- Store: 4x global_store_dwordx4, contiguous 1 KiB per wave
        // instruction (same pattern as the load and the 6.7 TB/s fills).
        y4[c * 256 + t] = res;
    }
}

extern "C" void kernel_launch(void* const* d_in, const int* in_sizes, int n_in,
                              void* d_out, int out_size, void* d_ws, size_t ws_size,
                              hipStream_t stream) {
    const float* x = (const float*)d_in[0];
    float* y = (float*)d_out;
    const int n = in_sizes[0];
    const int rows = n / DIM;  // 8192 for (4, 2048, 4096)
    fwht_kernel<<<rows, 256, 0, stream>>>(x, y);
}